// Round 8
// baseline (4164.971 us; speedup 1.0000x reference)
//
#include <hip/hip_runtime.h>
#include <float.h>

#define TT 4096
#define BB 4
#define CC 512
#define DD 256
#define KK 2048
#define MM (BB*TT)        // 16384 rows (b,t)
#define NBOOKS 22
#define EPS_REFINE 0.25f

typedef _Float16 half8_t __attribute__((ext_vector_type(8)));
typedef float f32x4 __attribute__((ext_vector_type(4)));

// merge (best value, best idx, second-best value) triples; ties -> lower idx (np.argmin semantics)
__device__ __forceinline__ void merge3(float& bv, int& bi, float& sv,
                                       float ov, int oi, float osv) {
  if (ov < bv || (ov == bv && oi < bi)) {
    sv = fminf(bv, osv);
    bv = ov; bi = oi;
  } else {
    sv = fminf(sv, ov);
  }
}

// ---------------- projection: xs = Win_s @ x, xa = Win_a @ x  (per b: [256x512]@[512x4096]) ----------------
__global__ __launch_bounds__(256) void proj_kernel(const float* __restrict__ x,
    const float* __restrict__ Ws, const float* __restrict__ Wa,
    float* __restrict__ xs, float* __restrict__ xa)
{
  __shared__ float xt[16*64];     // [c][t]
  __shared__ float wsl[16*68];    // [c][d] padded
  __shared__ float wal[16*68];
  const int tid = threadIdx.x;
  const int t0 = blockIdx.x*64, d0 = blockIdx.y*64, b = blockIdx.z;
  const int u = tid & 63, cq = tid >> 6;
  const int tx = tid & 15, ty = tid >> 4;
  const float* xb = x + (size_t)b*CC*TT;
  float accS[4][4] = {{0}}, accA[4][4] = {{0}};
  for (int c0 = 0; c0 < CC; c0 += 16) {
    __syncthreads();
    #pragma unroll
    for (int i = 0; i < 4; ++i) {
      int cc = cq*4 + i;
      xt[cc*64 + u] = xb[(size_t)(c0+cc)*TT + t0 + u];
    }
    {
      float4 wv = *(const float4*)&Ws[(size_t)(d0+u)*CC + c0 + cq*4];
      wsl[(cq*4+0)*68 + u] = wv.x; wsl[(cq*4+1)*68 + u] = wv.y;
      wsl[(cq*4+2)*68 + u] = wv.z; wsl[(cq*4+3)*68 + u] = wv.w;
      wv = *(const float4*)&Wa[(size_t)(d0+u)*CC + c0 + cq*4];
      wal[(cq*4+0)*68 + u] = wv.x; wal[(cq*4+1)*68 + u] = wv.y;
      wal[(cq*4+2)*68 + u] = wv.z; wal[(cq*4+3)*68 + u] = wv.w;
    }
    __syncthreads();
    #pragma unroll
    for (int cc = 0; cc < 16; ++cc) {
      float4 tq = *(const float4*)&xt[cc*64 + ty*4];
      float4 sq = *(const float4*)&wsl[cc*68 + tx*4];
      float4 aq = *(const float4*)&wal[cc*68 + tx*4];
      float tf[4] = {tq.x,tq.y,tq.z,tq.w};
      float sf[4] = {sq.x,sq.y,sq.z,sq.w};
      float af[4] = {aq.x,aq.y,aq.z,aq.w};
      #pragma unroll
      for (int i = 0; i < 4; ++i)
        #pragma unroll
        for (int j = 0; j < 4; ++j) {
          accS[i][j] = fmaf(tf[i], sf[j], accS[i][j]);
          accA[i][j] = fmaf(tf[i], af[j], accA[i][j]);
        }
    }
  }
  #pragma unroll
  for (int i = 0; i < 4; ++i) {
    size_t r = (size_t)b*TT + t0 + ty*4 + i;
    float4 o;
    o.x = accS[i][0]; o.y = accS[i][1]; o.z = accS[i][2]; o.w = accS[i][3];
    *(float4*)&xs[r*DD + d0 + tx*4] = o;
    o.x = accA[i][0]; o.y = accA[i][1]; o.z = accA[i][2]; o.w = accA[i][3];
    *(float4*)&xa[r*DD + d0 + tx*4] = o;
  }
}

// ---------------- e2[k] = sum_d E[k][d]^2 ----------------
__global__ __launch_bounds__(256) void e2_kernel(const float* __restrict__ E,
    float* __restrict__ e2)
{
  int gid = blockIdx.x*256 + threadIdx.x;
  int wid = gid >> 6, lane = gid & 63;
  if (wid < 18*KK) {
    float4 v = *(const float4*)&E[(size_t)wid*DD + lane*4];
    float s = v.x*v.x + v.y*v.y + v.z*v.z + v.w*v.w;
    #pragma unroll
    for (int m = 1; m <= 32; m <<= 1) s += __shfl_xor(s, m);
    if (lane == 0) e2[wid] = s;
  }
}

// ---------------- convert E -> f16 plane (stored in front of d_out, dead by final_kernel) ----------------
__global__ __launch_bounds__(256) void cvt_e16_kernel(const float* __restrict__ E,
    _Float16* __restrict__ E16)
{
  size_t i = ((size_t)blockIdx.x*256 + threadIdx.x)*8;
  float4 u = *(const float4*)&E[i];
  float4 v = *(const float4*)&E[i+4];
  half8_t h;
  h[0]=(_Float16)u.x; h[1]=(_Float16)u.y; h[2]=(_Float16)u.z; h[3]=(_Float16)u.w;
  h[4]=(_Float16)v.x; h[5]=(_Float16)v.y; h[6]=(_Float16)v.z; h[7]=(_Float16)v.w;
  *(half8_t*)&E16[i] = h;
}

// ---------------- FUSED encode: all 22 books in one kernel ----------------
// 256 blocks x 64 rows, 512 threads = 8 waves. Residual xa lives in LDS (f32).
// Per book: A-frag regen from LDS -> f16-MFMA search -> block reduce ->
// BATCHED in-block fp64 refine (book streamed once per <=8 flagged rows) ->
// f32 subtract in LDS. aco = xa_initial - xa_final at the end.
__global__ __launch_bounds__(512, 1) void fused_encode_kernel(
    const float* __restrict__ xs_g, const float* __restrict__ xa_g,
    const float* __restrict__ E, const _Float16* __restrict__ E16,
    const float* __restrict__ e2, int* __restrict__ codes0,
    float* __restrict__ codes_f, float* __restrict__ aco_g)
{
  const int tid = threadIdx.x;
  const int lane = tid & 63, wave = tid >> 6;
  const int ln15 = lane & 15, lq = lane >> 4;  // lq 0..3
  const int row0 = blockIdx.x * 64;

  __shared__ float Z[64][260];                 // residual panel, padded stride
  __shared__ float Lv[8][64], Ls[8][64];
  __shared__ int   Li[8][64];
  __shared__ int   codes_s[64];
  __shared__ int   flist[64];
  __shared__ int   nflag;
  __shared__ double Rv[8][8];
  __shared__ int    Ri[8][8];

  const int ldr = tid & 63, ldg = tid >> 6;    // panel-load / aco mapping
  const int sr = tid >> 3, sg = tid & 7;       // subtract mapping (8 lanes/row)

  for (int ib = 0; ib < NBOOKS; ++ib) {
    const int book = (ib <= 17) ? ib : 17;
    const float*     Eb   = E   + (size_t)book*KK*DD;
    const _Float16*  E16b = E16 + (size_t)book*KK*DD;
    const float*     e2b  = e2  + (size_t)book*KK;

    if (ib <= 1) {                             // ib0: xs panel; ib1: switch to xa panel
      const float* src = (ib == 0) ? xs_g : xa_g;
      const float* sp = src + (size_t)(row0 + ldr)*DD + ldg*32;
      #pragma unroll
      for (int j = 0; j < 8; ++j)
        *(float4*)&Z[ldr][ldg*32 + j*4] = *(const float4*)(sp + j*4);
    }
    if (tid == 0) nflag = 0;
    __syncthreads();                           // S1: Z + nflag ready

    // ---- A fragments from LDS (f32 -> f16) ----
    half8_t A[4][8];
    #pragma unroll
    for (int mt = 0; mt < 4; ++mt) {
      #pragma unroll
      for (int ks = 0; ks < 8; ++ks) {
        const float* zp = &Z[mt*16 + ln15][lq*8 + ks*32];
        float4 u = *(const float4*)zp;
        float4 v = *(const float4*)(zp + 4);
        half8_t a;
        a[0]=(_Float16)u.x; a[1]=(_Float16)u.y; a[2]=(_Float16)u.z; a[3]=(_Float16)u.w;
        a[4]=(_Float16)v.x; a[5]=(_Float16)v.y; a[6]=(_Float16)v.z; a[7]=(_Float16)v.w;
        A[mt][ks] = a;
      }
    }

    float bv[4][4], sv[4][4]; int bi[4][4];
    #pragma unroll
    for (int mt = 0; mt < 4; ++mt)
      #pragma unroll
      for (int j = 0; j < 4; ++j) { bv[mt][j] = FLT_MAX; sv[mt][j] = FLT_MAX; bi[mt][j] = 0x7fffffff; }

    const _Float16* ebase = E16b + (size_t)(wave*256 + ln15)*DD + lq*8;
    for (int nt = 0; nt < 16; ++nt) {
      const _Float16* bp = ebase + (size_t)nt*16*DD;
      half8_t B[8];
      #pragma unroll
      for (int ks = 0; ks < 8; ++ks) B[ks] = *(const half8_t*)(bp + ks*32);
      int code = wave*256 + nt*16 + ln15;
      float e2v = e2b[code];
      f32x4 acc[4];
      #pragma unroll
      for (int mt = 0; mt < 4; ++mt) acc[mt] = (f32x4){0.f,0.f,0.f,0.f};
      #pragma unroll
      for (int ks = 0; ks < 8; ++ks) {
        #pragma unroll
        for (int mt = 0; mt < 4; ++mt)
          acc[mt] = __builtin_amdgcn_mfma_f32_16x16x32_f16(A[mt][ks], B[ks], acc[mt], 0, 0, 0);
      }
      // C/D: col(code)=lane&15, row=(lane>>4)*4+reg
      #pragma unroll
      for (int mt = 0; mt < 4; ++mt)
        #pragma unroll
        for (int j = 0; j < 4; ++j) {
          float v = fmaf(-2.f, acc[mt][j], e2v);
          merge3(bv[mt][j], bi[mt][j], sv[mt][j], v, code, FLT_MAX);
        }
    }

    // ---- in-wave reduce over 16 code-columns, then cross-wave via LDS ----
    #pragma unroll
    for (int mt = 0; mt < 4; ++mt)
      #pragma unroll
      for (int j = 0; j < 4; ++j) {
        float v = bv[mt][j], s = sv[mt][j]; int ix = bi[mt][j];
        #pragma unroll
        for (int m = 1; m <= 8; m <<= 1) {
          float ov = __shfl_xor(v, m);
          int   oi = __shfl_xor(ix, m);
          float os = __shfl_xor(s, m);
          merge3(v, ix, s, ov, oi, os);
        }
        if (ln15 == 0) {
          int rl = mt*16 + lq*4 + j;
          Lv[wave][rl] = v; Li[wave][rl] = ix; Ls[wave][rl] = s;
        }
      }
    __syncthreads();                           // S2
    if (tid < 64) {
      float v = Lv[0][tid], s = Ls[0][tid]; int ix = Li[0][tid];
      #pragma unroll
      for (int w = 1; w < 8; ++w)
        merge3(v, ix, s, Lv[w][tid], Li[w][tid], Ls[w][tid]);
      codes_s[tid] = ix;
      int rg = row0 + tid;
      codes_f[((size_t)(rg >> 12)*NBOOKS + ib)*TT + (rg & (TT-1))] = (float)ix;
      if (ib == 0) codes0[rg] = ix;
      if (s - v < EPS_REFINE) {
        int p = atomicAdd(&nflag, 1);
        flist[p] = tid;
      }
    }
    __syncthreads();                           // S3: codes_s, flist, nflag visible

    // ---- batched fp64 refine: book streamed ONCE per batch of <=8 rows ----
    int nfl = nflag;
    for (int base = 0; base < nfl; base += 8) {
      int F = nfl - base; if (F > 8) F = 8;
      int rw[8];
      #pragma unroll
      for (int f = 0; f < 8; ++f) rw[f] = flist[base + (f < F ? f : 0)];
      double bestv[8]; int besti[8];
      #pragma unroll
      for (int f = 0; f < 8; ++f) { bestv[f] = DBL_MAX; besti[f] = 0x7fffffff; }
      #pragma unroll
      for (int q = 0; q < 4; ++q) {
        int k = q*512 + tid;
        const float* er = Eb + (size_t)k*DD;
        double acc[8];
        #pragma unroll
        for (int f = 0; f < 8; ++f) acc[f] = 0.0;
        for (int d = 0; d < DD; d += 4) {
          float4 e = *(const float4*)(er + d);
          #pragma unroll
          for (int f = 0; f < 8; ++f) {
            double d0 = (double)Z[rw[f]][d+0] - (double)e.x;
            double d1 = (double)Z[rw[f]][d+1] - (double)e.y;
            double d2 = (double)Z[rw[f]][d+2] - (double)e.z;
            double d3 = (double)Z[rw[f]][d+3] - (double)e.w;
            acc[f] += d0*d0 + d1*d1 + d2*d2 + d3*d3;
          }
        }
        #pragma unroll
        for (int f = 0; f < 8; ++f)
          if (acc[f] < bestv[f] || (acc[f] == bestv[f] && k < besti[f])) {
            bestv[f] = acc[f]; besti[f] = k;
          }
      }
      // intra-wave reduce per slot, then cross-wave
      #pragma unroll
      for (int f = 0; f < 8; ++f) {
        double v = bestv[f]; int ix = besti[f];
        #pragma unroll
        for (int m = 1; m <= 32; m <<= 1) {
          double ov = __shfl_xor(v, m);
          int    oi = __shfl_xor(ix, m);
          if (ov < v || (ov == v && oi < ix)) { v = ov; ix = oi; }
        }
        if (lane == 0) { Rv[wave][f] = v; Ri[wave][f] = ix; }
      }
      __syncthreads();
      if (tid < F) {
        double v = Rv[0][tid]; int ix = Ri[0][tid];
        #pragma unroll
        for (int w = 1; w < 8; ++w)
          if (Rv[w][tid] < v || (Rv[w][tid] == v && Ri[w][tid] < ix)) {
            v = Rv[w][tid]; ix = Ri[w][tid];
          }
        int row = flist[base + tid];
        codes_s[row] = ix;
        int rg = row0 + row;
        codes_f[((size_t)(rg >> 12)*NBOOKS + ib)*TT + (rg & (TT-1))] = (float)ix;
        if (ib == 0) codes0[rg] = ix;
      }
      __syncthreads();
    }

    // ---- f32 residual subtract in LDS (acoustic books only) ----
    if (ib >= 1) {
      int code = codes_s[sr];
      const float* er = Eb + (size_t)code*DD;
      #pragma unroll
      for (int j = 0; j < 8; ++j) {
        int c = sg*4 + j*32;
        float4 e = *(const float4*)(er + c);
        float4 z = *(const float4*)&Z[sr][c];
        z.x -= e.x; z.y -= e.y; z.z -= e.z; z.w -= e.w;
        *(float4*)&Z[sr][c] = z;
      }
    }
    __syncthreads();                           // S5: Z stable for next book
  }

  // ---- aco = xa_initial - xa_final ----
  {
    const float* xp = xa_g + (size_t)(row0 + ldr)*DD + ldg*32;
    float*       ap = aco_g + (size_t)(row0 + ldr)*DD + ldg*32;
    #pragma unroll
    for (int j = 0; j < 8; ++j) {
      float4 x0 = *(const float4*)(xp + j*4);
      float4 zf = *(const float4*)&Z[ldr][ldg*32 + j*4];
      float4 o;
      o.x = x0.x - zf.x; o.y = x0.y - zf.y; o.z = x0.z - zf.z; o.w = x0.w - zf.w;
      *(float4*)(ap + j*4) = o;
    }
  }
}

// ---------------- decode ----------------
__global__ __launch_bounds__(256) void final_kernel(
    const float* __restrict__ Wos, const float* __restrict__ Woa,
    const float* __restrict__ E0, const int* __restrict__ codes0,
    const float* __restrict__ aco, float* __restrict__ out)
{
  __shared__ float wsl[16*68], wal[16*68], sml[16*68], acl[16*68];
  const int tid = threadIdx.x;
  const int t0 = blockIdx.x*64, c0 = blockIdx.y*64, b = blockIdx.z;
  const int u = tid & 63, dq = tid >> 6;
  const int tx = tid & 15, ty = tid >> 4;
  int code = codes0[b*TT + t0 + u];
  const float* smr = E0 + (size_t)code*DD;
  const float* acr = aco + (size_t)(b*TT + t0 + u)*DD;
  const float* wsr = Wos + (size_t)(c0+u)*DD;
  const float* war = Woa + (size_t)(c0+u)*DD;
  float accS[4][4] = {{0}}, accA[4][4] = {{0}};
  for (int dc0 = 0; dc0 < DD; dc0 += 16) {
    __syncthreads();
    float4 v;
    v = *(const float4*)(wsr + dc0 + dq*4);
    wsl[(dq*4+0)*68+u]=v.x; wsl[(dq*4+1)*68+u]=v.y; wsl[(dq*4+2)*68+u]=v.z; wsl[(dq*4+3)*68+u]=v.w;
    v = *(const float4*)(war + dc0 + dq*4);
    wal[(dq*4+0)*68+u]=v.x; wal[(dq*4+1)*68+u]=v.y; wal[(dq*4+2)*68+u]=v.z; wal[(dq*4+3)*68+u]=v.w;
    v = *(const float4*)(smr + dc0 + dq*4);
    sml[(dq*4+0)*68+u]=v.x; sml[(dq*4+1)*68+u]=v.y; sml[(dq*4+2)*68+u]=v.z; sml[(dq*4+3)*68+u]=v.w;
    v = *(const float4*)(acr + dc0 + dq*4);
    acl[(dq*4+0)*68+u]=v.x; acl[(dq*4+1)*68+u]=v.y; acl[(dq*4+2)*68+u]=v.z; acl[(dq*4+3)*68+u]=v.w;
    __syncthreads();
    #pragma unroll
    for (int d = 0; d < 16; ++d) {
      float4 cs = *(const float4*)&wsl[d*68 + tx*4];
      float4 ca = *(const float4*)&wal[d*68 + tx*4];
      float4 ts = *(const float4*)&sml[d*68 + ty*4];
      float4 ta = *(const float4*)&acl[d*68 + ty*4];
      float csf[4]={cs.x,cs.y,cs.z,cs.w}, caf[4]={ca.x,ca.y,ca.z,ca.w};
      float tsf[4]={ts.x,ts.y,ts.z,ts.w}, taf[4]={ta.x,ta.y,ta.z,ta.w};
      #pragma unroll
      for (int i = 0; i < 4; ++i)
        #pragma unroll
        for (int j = 0; j < 4; ++j) {
          accS[i][j] = fmaf(csf[i], tsf[j], accS[i][j]);
          accA[i][j] = fmaf(caf[i], taf[j], accA[i][j]);
        }
    }
  }
  size_t ob = (size_t)b*CC*TT;
  #pragma unroll
  for (int i = 0; i < 4; ++i) {
    float4 r;
    r.x = accS[i][0] + accA[i][0];
    r.y = accS[i][1] + accA[i][1];
    r.z = accS[i][2] + accA[i][2];
    r.w = accS[i][3] + accA[i][3];
    *(float4*)&out[ob + (size_t)(c0 + tx*4 + i)*TT + t0 + ty*4] = r;
  }
}

extern "C" void kernel_launch(void* const* d_in, const int* in_sizes, int n_in,
                              void* d_out, int out_size, void* d_ws, size_t ws_size,
                              hipStream_t stream) {
  const float* x    = (const float*)d_in[0];
  const float* Wins = (const float*)d_in[1];
  const float* Wina = (const float*)d_in[2];
  const float* Wos  = (const float*)d_in[3];
  const float* Woa  = (const float*)d_in[4];
  const float* E    = (const float*)d_in[5];
  float* out = (float*)d_out;
  float* codes_f = out + (size_t)BB*CC*TT;

  // E16 plane lives in the front of d_out (18.9MB; codes_f starts at 33.6MB;
  // out[0:8.4M floats] fully overwritten by final_kernel afterwards).
  _Float16* E16 = (_Float16*)d_out;

  float* xs  = (float*)d_ws;
  float* xa  = xs + (size_t)MM*DD;
  float* aco = xa + (size_t)MM*DD;
  float* e2  = aco + (size_t)MM*DD;
  int* codes_i = (int*)(e2 + 18*KK);

  proj_kernel<<<dim3(TT/64, DD/64, BB), 256, 0, stream>>>(x, Wins, Wina, xs, xa);
  e2_kernel<<<(18*KK*64)/256, 256, 0, stream>>>(E, e2);
  cvt_e16_kernel<<<(18*KK*DD)/8/256, 256, 0, stream>>>(E, E16);

  fused_encode_kernel<<<MM/64, 512, 0, stream>>>(xs, xa, E, E16, e2,
                                                 codes_i, codes_f, aco);

  final_kernel<<<dim3(TT/64, CC/64, BB), 256, 0, stream>>>(Wos, Woa, E, codes_i, aco, out);
}

// Round 9
// 3721.525 us; speedup vs baseline: 1.1192x; 1.1192x over previous
//
#include <hip/hip_runtime.h>
#include <float.h>

#define TT 4096
#define BB 4
#define CC 512
#define DD 256
#define KK 2048
#define MM (BB*TT)        // 16384 rows (b,t)
#define NBOOKS 22
#define EPS_REFINE 0.25f
#define ZSTR 324          // Z row stride (floats): 64*324*4 = 83KB -> 1 block/CU

typedef _Float16 half8_t __attribute__((ext_vector_type(8)));
typedef float f32x4 __attribute__((ext_vector_type(4)));

// merge (best value, best idx, second-best value) triples; ties -> lower idx (np.argmin semantics)
__device__ __forceinline__ void merge3(float& bv, int& bi, float& sv,
                                       float ov, int oi, float osv) {
  if (ov < bv || (ov == bv && oi < bi)) {
    sv = fminf(bv, osv);
    bv = ov; bi = oi;
  } else {
    sv = fminf(sv, ov);
  }
}

// ---------------- projection: xs = Win_s @ x, xa = Win_a @ x  (per b: [256x512]@[512x4096]) ----------------
__global__ __launch_bounds__(256) void proj_kernel(const float* __restrict__ x,
    const float* __restrict__ Ws, const float* __restrict__ Wa,
    float* __restrict__ xs, float* __restrict__ xa)
{
  __shared__ float xt[16*64];     // [c][t]
  __shared__ float wsl[16*68];    // [c][d] padded
  __shared__ float wal[16*68];
  const int tid = threadIdx.x;
  const int t0 = blockIdx.x*64, d0 = blockIdx.y*64, b = blockIdx.z;
  const int u = tid & 63, cq = tid >> 6;
  const int tx = tid & 15, ty = tid >> 4;
  const float* xb = x + (size_t)b*CC*TT;
  float accS[4][4] = {{0}}, accA[4][4] = {{0}};
  for (int c0 = 0; c0 < CC; c0 += 16) {
    __syncthreads();
    #pragma unroll
    for (int i = 0; i < 4; ++i) {
      int cc = cq*4 + i;
      xt[cc*64 + u] = xb[(size_t)(c0+cc)*TT + t0 + u];
    }
    {
      float4 wv = *(const float4*)&Ws[(size_t)(d0+u)*CC + c0 + cq*4];
      wsl[(cq*4+0)*68 + u] = wv.x; wsl[(cq*4+1)*68 + u] = wv.y;
      wsl[(cq*4+2)*68 + u] = wv.z; wsl[(cq*4+3)*68 + u] = wv.w;
      wv = *(const float4*)&Wa[(size_t)(d0+u)*CC + c0 + cq*4];
      wal[(cq*4+0)*68 + u] = wv.x; wal[(cq*4+1)*68 + u] = wv.y;
      wal[(cq*4+2)*68 + u] = wv.z; wal[(cq*4+3)*68 + u] = wv.w;
    }
    __syncthreads();
    #pragma unroll
    for (int cc = 0; cc < 16; ++cc) {
      float4 tq = *(const float4*)&xt[cc*64 + ty*4];
      float4 sq = *(const float4*)&wsl[cc*68 + tx*4];
      float4 aq = *(const float4*)&wal[cc*68 + tx*4];
      float tf[4] = {tq.x,tq.y,tq.z,tq.w};
      float sf[4] = {sq.x,sq.y,sq.z,sq.w};
      float af[4] = {aq.x,aq.y,aq.z,aq.w};
      #pragma unroll
      for (int i = 0; i < 4; ++i)
        #pragma unroll
        for (int j = 0; j < 4; ++j) {
          accS[i][j] = fmaf(tf[i], sf[j], accS[i][j]);
          accA[i][j] = fmaf(tf[i], af[j], accA[i][j]);
        }
    }
  }
  #pragma unroll
  for (int i = 0; i < 4; ++i) {
    size_t r = (size_t)b*TT + t0 + ty*4 + i;
    float4 o;
    o.x = accS[i][0]; o.y = accS[i][1]; o.z = accS[i][2]; o.w = accS[i][3];
    *(float4*)&xs[r*DD + d0 + tx*4] = o;
    o.x = accA[i][0]; o.y = accA[i][1]; o.z = accA[i][2]; o.w = accA[i][3];
    *(float4*)&xa[r*DD + d0 + tx*4] = o;
  }
}

// ---------------- e2[k] = sum_d E[k][d]^2 ----------------
__global__ __launch_bounds__(256) void e2_kernel(const float* __restrict__ E,
    float* __restrict__ e2)
{
  int gid = blockIdx.x*256 + threadIdx.x;
  int wid = gid >> 6, lane = gid & 63;
  if (wid < 18*KK) {
    float4 v = *(const float4*)&E[(size_t)wid*DD + lane*4];
    float s = v.x*v.x + v.y*v.y + v.z*v.z + v.w*v.w;
    #pragma unroll
    for (int m = 1; m <= 32; m <<= 1) s += __shfl_xor(s, m);
    if (lane == 0) e2[wid] = s;
  }
}

// ---------------- convert E -> f16 plane (stored in front of d_out, dead by final_kernel) ----------------
__global__ __launch_bounds__(256) void cvt_e16_kernel(const float* __restrict__ E,
    _Float16* __restrict__ E16)
{
  size_t i = ((size_t)blockIdx.x*256 + threadIdx.x)*8;
  float4 u = *(const float4*)&E[i];
  float4 v = *(const float4*)&E[i+4];
  half8_t h;
  h[0]=(_Float16)u.x; h[1]=(_Float16)u.y; h[2]=(_Float16)u.z; h[3]=(_Float16)u.w;
  h[4]=(_Float16)v.x; h[5]=(_Float16)v.y; h[6]=(_Float16)v.z; h[7]=(_Float16)v.w;
  *(half8_t*)&E16[i] = h;
}

// ---------------- FUSED encode: all 22 books in one kernel ----------------
// 256 blocks x 64 rows, 512 threads = 8 waves, 1 block/CU (LDS ~90KB).
// amdgpu_waves_per_eu(2) => 256-VGPR budget so A[4][8] stays in registers.
// Per book: A-frag regen from LDS -> f16-MFMA search (prefetched B) ->
// block reduce -> per-row fp64 refine of near-ties -> f32 subtract in LDS.
// aco = xa_initial - xa_final at the end.
__global__ __launch_bounds__(512) __attribute__((amdgpu_waves_per_eu(2)))
void fused_encode_kernel(
    const float* __restrict__ xs_g, const float* __restrict__ xa_g,
    const float* __restrict__ E, const _Float16* __restrict__ E16,
    const float* __restrict__ e2, int* __restrict__ codes0,
    float* __restrict__ codes_f, float* __restrict__ aco_g)
{
  const int tid = threadIdx.x;
  const int lane = tid & 63, wave = tid >> 6;
  const int ln15 = lane & 15, lq = lane >> 4;  // lq 0..3
  const int row0 = blockIdx.x * 64;

  __shared__ float Z[64][ZSTR];                // residual panel (83KB -> 1 block/CU)
  __shared__ float Lv[8][64], Ls[8][64];
  __shared__ int   Li[8][64];
  __shared__ int   codes_s[64];
  __shared__ int   flist[64];
  __shared__ int   nflag;
  __shared__ float zrow[DD];
  __shared__ double Rv[8];
  __shared__ int    Ri[8];

  const int ldr = tid & 63, ldg = tid >> 6;    // panel-load / aco mapping
  const int sr = tid >> 3, sg = tid & 7;       // subtract mapping (8 lanes/row)

  for (int ib = 0; ib < NBOOKS; ++ib) {
    const int book = (ib <= 17) ? ib : 17;
    const float*     Eb   = E   + (size_t)book*KK*DD;
    const _Float16*  E16b = E16 + (size_t)book*KK*DD;
    const float*     e2b  = e2  + (size_t)book*KK;

    if (ib <= 1) {                             // ib0: xs panel; ib1: switch to xa panel
      const float* src = (ib == 0) ? xs_g : xa_g;
      const float* sp = src + (size_t)(row0 + ldr)*DD + ldg*32;
      #pragma unroll
      for (int j = 0; j < 8; ++j)
        *(float4*)&Z[ldr][ldg*32 + j*4] = *(const float4*)(sp + j*4);
    }
    if (tid == 0) nflag = 0;
    __syncthreads();                           // S1: Z + nflag ready

    // ---- A fragments from LDS (f32 -> f16) ----
    half8_t A[4][8];
    #pragma unroll
    for (int mt = 0; mt < 4; ++mt) {
      #pragma unroll
      for (int ks = 0; ks < 8; ++ks) {
        const float* zp = &Z[mt*16 + ln15][lq*8 + ks*32];
        float4 u = *(const float4*)zp;
        float4 v = *(const float4*)(zp + 4);
        half8_t a;
        a[0]=(_Float16)u.x; a[1]=(_Float16)u.y; a[2]=(_Float16)u.z; a[3]=(_Float16)u.w;
        a[4]=(_Float16)v.x; a[5]=(_Float16)v.y; a[6]=(_Float16)v.z; a[7]=(_Float16)v.w;
        A[mt][ks] = a;
      }
    }

    float bv[4][4], sv[4][4]; int bi[4][4];
    #pragma unroll
    for (int mt = 0; mt < 4; ++mt)
      #pragma unroll
      for (int j = 0; j < 4; ++j) { bv[mt][j] = FLT_MAX; sv[mt][j] = FLT_MAX; bi[mt][j] = 0x7fffffff; }

    const _Float16* ebase = E16b + (size_t)(wave*256 + ln15)*DD + lq*8;

    half8_t B[8], NB[4];
    #pragma unroll
    for (int ks = 0; ks < 8; ++ks) B[ks] = *(const half8_t*)(ebase + ks*32);

    for (int nt = 0; nt < 16; ++nt) {
      const _Float16* nx = ebase + (size_t)(nt+1)*16*DD;
      if (nt < 15) {                           // prefetch next-nt k0..3
        NB[0] = *(const half8_t*)(nx + 0*32);
        NB[1] = *(const half8_t*)(nx + 1*32);
        NB[2] = *(const half8_t*)(nx + 2*32);
        NB[3] = *(const half8_t*)(nx + 3*32);
      }
      int code = wave*256 + nt*16 + ln15;
      float e2v = e2b[code];
      f32x4 acc[4];
      #pragma unroll
      for (int mt = 0; mt < 4; ++mt) acc[mt] = (f32x4){0.f,0.f,0.f,0.f};
      #pragma unroll
      for (int ks = 0; ks < 8; ++ks) {
        #pragma unroll
        for (int mt = 0; mt < 4; ++mt)
          acc[mt] = __builtin_amdgcn_mfma_f32_16x16x32_f16(A[mt][ks], B[ks], acc[mt], 0, 0, 0);
      }
      // C/D: col(code)=lane&15, row=(lane>>4)*4+reg
      #pragma unroll
      for (int mt = 0; mt < 4; ++mt)
        #pragma unroll
        for (int j = 0; j < 4; ++j) {
          float v = fmaf(-2.f, acc[mt][j], e2v);
          merge3(bv[mt][j], bi[mt][j], sv[mt][j], v, code, FLT_MAX);
        }
      if (nt < 15) {                           // rotate + reissue k4..7 of next nt
        B[0] = NB[0]; B[1] = NB[1]; B[2] = NB[2]; B[3] = NB[3];
        B[4] = *(const half8_t*)(nx + 4*32);
        B[5] = *(const half8_t*)(nx + 5*32);
        B[6] = *(const half8_t*)(nx + 6*32);
        B[7] = *(const half8_t*)(nx + 7*32);
      }
    }

    // ---- in-wave reduce over 16 code-columns, then cross-wave via LDS ----
    #pragma unroll
    for (int mt = 0; mt < 4; ++mt)
      #pragma unroll
      for (int j = 0; j < 4; ++j) {
        float v = bv[mt][j], s = sv[mt][j]; int ix = bi[mt][j];
        #pragma unroll
        for (int m = 1; m <= 8; m <<= 1) {
          float ov = __shfl_xor(v, m);
          int   oi = __shfl_xor(ix, m);
          float os = __shfl_xor(s, m);
          merge3(v, ix, s, ov, oi, os);
        }
        if (ln15 == 0) {
          int rl = mt*16 + lq*4 + j;
          Lv[wave][rl] = v; Li[wave][rl] = ix; Ls[wave][rl] = s;
        }
      }
    __syncthreads();                           // S2
    if (tid < 64) {
      float v = Lv[0][tid], s = Ls[0][tid]; int ix = Li[0][tid];
      #pragma unroll
      for (int w = 1; w < 8; ++w)
        merge3(v, ix, s, Lv[w][tid], Li[w][tid], Ls[w][tid]);
      codes_s[tid] = ix;
      int rg = row0 + tid;
      codes_f[((size_t)(rg >> 12)*NBOOKS + ib)*TT + (rg & (TT-1))] = (float)ix;
      if (ib == 0) codes0[rg] = ix;
      if (s - v < EPS_REFINE) {
        int p = atomicAdd(&nflag, 1);
        flist[p] = tid;
      }
    }
    __syncthreads();                           // S3: codes_s, flist, nflag visible

    // ---- per-row fp64 refine of near-tie rows (whole block per row) ----
    int nfl = nflag;
    for (int f = 0; f < nfl; ++f) {
      int row = flist[f];
      if (tid < 64)
        *(float4*)&zrow[tid*4] = *(const float4*)&Z[row][tid*4];
      __syncthreads();
      double bestv = DBL_MAX; int besti = 0x7fffffff;
      #pragma unroll
      for (int q = 0; q < 4; ++q) {
        int k = q*512 + tid;
        const float* er = Eb + (size_t)k*DD;
        double s = 0.0;
        for (int d = 0; d < DD; d += 4) {
          float4 e = *(const float4*)(er + d);
          double d0 = (double)zrow[d+0] - (double)e.x; s += d0*d0;
          double d1 = (double)zrow[d+1] - (double)e.y; s += d1*d1;
          double d2 = (double)zrow[d+2] - (double)e.z; s += d2*d2;
          double d3 = (double)zrow[d+3] - (double)e.w; s += d3*d3;
        }
        if (s < bestv || (s == bestv && k < besti)) { bestv = s; besti = k; }
      }
      #pragma unroll
      for (int m = 1; m <= 32; m <<= 1) {
        double ov = __shfl_xor(bestv, m);
        int    oi = __shfl_xor(besti, m);
        if (ov < bestv || (ov == bestv && oi < besti)) { bestv = ov; besti = oi; }
      }
      if (lane == 0) { Rv[wave] = bestv; Ri[wave] = besti; }
      __syncthreads();
      if (tid == 0) {
        double bvv = Rv[0]; int bii = Ri[0];
        #pragma unroll
        for (int w = 1; w < 8; ++w)
          if (Rv[w] < bvv || (Rv[w] == bvv && Ri[w] < bii)) { bvv = Rv[w]; bii = Ri[w]; }
        codes_s[row] = bii;
        int rg = row0 + row;
        codes_f[((size_t)(rg >> 12)*NBOOKS + ib)*TT + (rg & (TT-1))] = (float)bii;
        if (ib == 0) codes0[rg] = bii;
      }
      __syncthreads();                         // codes_s update + zrow reuse safe
    }

    // ---- f32 residual subtract in LDS (acoustic books only) ----
    if (ib >= 1) {
      int code = codes_s[sr];
      const float* er = Eb + (size_t)code*DD;
      #pragma unroll
      for (int j = 0; j < 8; ++j) {
        int c = sg*4 + j*32;
        float4 e = *(const float4*)(er + c);
        float4 z = *(const float4*)&Z[sr][c];
        z.x -= e.x; z.y -= e.y; z.z -= e.z; z.w -= e.w;
        *(float4*)&Z[sr][c] = z;
      }
    }
    __syncthreads();                           // S5: Z stable for next book
  }

  // ---- aco = xa_initial - xa_final ----
  {
    const float* xp = xa_g + (size_t)(row0 + ldr)*DD + ldg*32;
    float*       ap = aco_g + (size_t)(row0 + ldr)*DD + ldg*32;
    #pragma unroll
    for (int j = 0; j < 8; ++j) {
      float4 x0 = *(const float4*)(xp + j*4);
      float4 zf = *(const float4*)&Z[ldr][ldg*32 + j*4];
      float4 o;
      o.x = x0.x - zf.x; o.y = x0.y - zf.y; o.z = x0.z - zf.z; o.w = x0.w - zf.w;
      *(float4*)(ap + j*4) = o;
    }
  }
}

// ---------------- decode ----------------
__global__ __launch_bounds__(256) void final_kernel(
    const float* __restrict__ Wos, const float* __restrict__ Woa,
    const float* __restrict__ E0, const int* __restrict__ codes0,
    const float* __restrict__ aco, float* __restrict__ out)
{
  __shared__ float wsl[16*68], wal[16*68], sml[16*68], acl[16*68];
  const int tid = threadIdx.x;
  const int t0 = blockIdx.x*64, c0 = blockIdx.y*64, b = blockIdx.z;
  const int u = tid & 63, dq = tid >> 6;
  const int tx = tid & 15, ty = tid >> 4;
  int code = codes0[b*TT + t0 + u];
  const float* smr = E0 + (size_t)code*DD;
  const float* acr = aco + (size_t)(b*TT + t0 + u)*DD;
  const float* wsr = Wos + (size_t)(c0+u)*DD;
  const float* war = Woa + (size_t)(c0+u)*DD;
  float accS[4][4] = {{0}}, accA[4][4] = {{0}};
  for (int dc0 = 0; dc0 < DD; dc0 += 16) {
    __syncthreads();
    float4 v;
    v = *(const float4*)(wsr + dc0 + dq*4);
    wsl[(dq*4+0)*68+u]=v.x; wsl[(dq*4+1)*68+u]=v.y; wsl[(dq*4+2)*68+u]=v.z; wsl[(dq*4+3)*68+u]=v.w;
    v = *(const float4*)(war + dc0 + dq*4);
    wal[(dq*4+0)*68+u]=v.x; wal[(dq*4+1)*68+u]=v.y; wal[(dq*4+2)*68+u]=v.z; wal[(dq*4+3)*68+u]=v.w;
    v = *(const float4*)(smr + dc0 + dq*4);
    sml[(dq*4+0)*68+u]=v.x; sml[(dq*4+1)*68+u]=v.y; sml[(dq*4+2)*68+u]=v.z; sml[(dq*4+3)*68+u]=v.w;
    v = *(const float4*)(acr + dc0 + dq*4);
    acl[(dq*4+0)*68+u]=v.x; acl[(dq*4+1)*68+u]=v.y; acl[(dq*4+2)*68+u]=v.z; acl[(dq*4+3)*68+u]=v.w;
    __syncthreads();
    #pragma unroll
    for (int d = 0; d < 16; ++d) {
      float4 cs = *(const float4*)&wsl[d*68 + tx*4];
      float4 ca = *(const float4*)&wal[d*68 + tx*4];
      float4 ts = *(const float4*)&sml[d*68 + ty*4];
      float4 ta = *(const float4*)&acl[d*68 + ty*4];
      float csf[4]={cs.x,cs.y,cs.z,cs.w}, caf[4]={ca.x,ca.y,ca.z,ca.w};
      float tsf[4]={ts.x,ts.y,ts.z,ts.w}, taf[4]={ta.x,ta.y,ta.z,ta.w};
      #pragma unroll
      for (int i = 0; i < 4; ++i)
        #pragma unroll
        for (int j = 0; j < 4; ++j) {
          accS[i][j] = fmaf(csf[i], tsf[j], accS[i][j]);
          accA[i][j] = fmaf(caf[i], taf[j], accA[i][j]);
        }
    }
  }
  size_t ob = (size_t)b*CC*TT;
  #pragma unroll
  for (int i = 0; i < 4; ++i) {
    float4 r;
    r.x = accS[i][0] + accA[i][0];
    r.y = accS[i][1] + accA[i][1];
    r.z = accS[i][2] + accA[i][2];
    r.w = accS[i][3] + accA[i][3];
    *(float4*)&out[ob + (size_t)(c0 + tx*4 + i)*TT + t0 + ty*4] = r;
  }
}

extern "C" void kernel_launch(void* const* d_in, const int* in_sizes, int n_in,
                              void* d_out, int out_size, void* d_ws, size_t ws_size,
                              hipStream_t stream) {
  const float* x    = (const float*)d_in[0];
  const float* Wins = (const float*)d_in[1];
  const float* Wina = (const float*)d_in[2];
  const float* Wos  = (const float*)d_in[3];
  const float* Woa  = (const float*)d_in[4];
  const float* E    = (const float*)d_in[5];
  float* out = (float*)d_out;
  float* codes_f = out + (size_t)BB*CC*TT;

  // E16 plane lives in the front of d_out (18.9MB; codes_f starts at 33.6MB;
  // out[0:8.4M floats] fully overwritten by final_kernel afterwards).
  _Float16* E16 = (_Float16*)d_out;

  float* xs  = (float*)d_ws;
  float* xa  = xs + (size_t)MM*DD;
  float* aco = xa + (size_t)MM*DD;
  float* e2  = aco + (size_t)MM*DD;
  int* codes_i = (int*)(e2 + 18*KK);

  proj_kernel<<<dim3(TT/64, DD/64, BB), 256, 0, stream>>>(x, Wins, Wina, xs, xa);
  e2_kernel<<<(18*KK*64)/256, 256, 0, stream>>>(E, e2);
  cvt_e16_kernel<<<(18*KK*DD)/8/256, 256, 0, stream>>>(E, E16);

  fused_encode_kernel<<<MM/64, 512, 0, stream>>>(xs, xa, E, E16, e2,
                                                 codes_i, codes_f, aco);

  final_kernel<<<dim3(TT/64, CC/64, BB), 256, 0, stream>>>(Wos, Woa, E, codes_i, aco, out);
}

// Round 10
// 2426.519 us; speedup vs baseline: 1.7164x; 1.5337x over previous
//
#include <hip/hip_runtime.h>
#include <float.h>

#define TT 4096
#define BB 4
#define CC 512
#define DD 256
#define KK 2048
#define MM (BB*TT)        // 16384 rows (b,t)
#define NBOOKS 22
#define EPS_PAIR 0.3f
#define EPS_FULL 0.3f
#define ZSTR 260

typedef _Float16 half8_t __attribute__((ext_vector_type(8)));
typedef float f32x4 __attribute__((ext_vector_type(4)));

// ---- top-3 tracking: (best v1,i1), (second v2,i2), (third value v3) ----
// ties -> lower index (np.argmin semantics, resolved exactly in fp64 later)
__device__ __forceinline__ void insert3(float& v1, int& i1, float& v2, int& i2,
                                        float& v3, float u, int c) {
  if (u < v1 || (u == v1 && c < i1)) {
    v3 = v2; v2 = v1; i2 = i1; v1 = u; i1 = c;
  } else if (u < v2 || (u == v2 && c < i2)) {
    v3 = v2; v2 = u; i2 = c;
  } else {
    v3 = fminf(v3, u);
  }
}

__device__ __forceinline__ void merge5(float& v1, int& i1, float& v2, int& i2,
                                       float& v3,
                                       float w1, int j1, float w2, int j2, float w3) {
  if (w1 < v1 || (w1 == v1 && j1 < i1)) {
    if (v1 < w2 || (v1 == w2 && i1 < j2)) {
      v3 = fminf(v2, w2);
      v2 = v1; i2 = i1;
    } else {
      v3 = fminf(v1, w3);
      v2 = w2; i2 = j2;
    }
    v1 = w1; i1 = j1;
  } else {
    if (w1 < v2 || (w1 == v2 && j1 < i2)) {
      v3 = fminf(v2, w2);
      v2 = w1; i2 = j1;
    } else {
      v3 = fminf(w1, v3);
    }
  }
}

// ---------------- projection: xs = Win_s @ x, xa = Win_a @ x ----------------
__global__ __launch_bounds__(256) void proj_kernel(const float* __restrict__ x,
    const float* __restrict__ Ws, const float* __restrict__ Wa,
    float* __restrict__ xs, float* __restrict__ xa)
{
  __shared__ float xt[16*64];
  __shared__ float wsl[16*68];
  __shared__ float wal[16*68];
  const int tid = threadIdx.x;
  const int t0 = blockIdx.x*64, d0 = blockIdx.y*64, b = blockIdx.z;
  const int u = tid & 63, cq = tid >> 6;
  const int tx = tid & 15, ty = tid >> 4;
  const float* xb = x + (size_t)b*CC*TT;
  float accS[4][4] = {{0}}, accA[4][4] = {{0}};
  for (int c0 = 0; c0 < CC; c0 += 16) {
    __syncthreads();
    #pragma unroll
    for (int i = 0; i < 4; ++i) {
      int cc = cq*4 + i;
      xt[cc*64 + u] = xb[(size_t)(c0+cc)*TT + t0 + u];
    }
    {
      float4 wv = *(const float4*)&Ws[(size_t)(d0+u)*CC + c0 + cq*4];
      wsl[(cq*4+0)*68 + u] = wv.x; wsl[(cq*4+1)*68 + u] = wv.y;
      wsl[(cq*4+2)*68 + u] = wv.z; wsl[(cq*4+3)*68 + u] = wv.w;
      wv = *(const float4*)&Wa[(size_t)(d0+u)*CC + c0 + cq*4];
      wal[(cq*4+0)*68 + u] = wv.x; wal[(cq*4+1)*68 + u] = wv.y;
      wal[(cq*4+2)*68 + u] = wv.z; wal[(cq*4+3)*68 + u] = wv.w;
    }
    __syncthreads();
    #pragma unroll
    for (int cc = 0; cc < 16; ++cc) {
      float4 tq = *(const float4*)&xt[cc*64 + ty*4];
      float4 sq = *(const float4*)&wsl[cc*68 + tx*4];
      float4 aq = *(const float4*)&wal[cc*68 + tx*4];
      float tf[4] = {tq.x,tq.y,tq.z,tq.w};
      float sf[4] = {sq.x,sq.y,sq.z,sq.w};
      float af[4] = {aq.x,aq.y,aq.z,aq.w};
      #pragma unroll
      for (int i = 0; i < 4; ++i)
        #pragma unroll
        for (int j = 0; j < 4; ++j) {
          accS[i][j] = fmaf(tf[i], sf[j], accS[i][j]);
          accA[i][j] = fmaf(tf[i], af[j], accA[i][j]);
        }
    }
  }
  #pragma unroll
  for (int i = 0; i < 4; ++i) {
    size_t r = (size_t)b*TT + t0 + ty*4 + i;
    float4 o;
    o.x = accS[i][0]; o.y = accS[i][1]; o.z = accS[i][2]; o.w = accS[i][3];
    *(float4*)&xs[r*DD + d0 + tx*4] = o;
    o.x = accA[i][0]; o.y = accA[i][1]; o.z = accA[i][2]; o.w = accA[i][3];
    *(float4*)&xa[r*DD + d0 + tx*4] = o;
  }
}

// ---------------- e2[k] = sum_d E[k][d]^2 ----------------
__global__ __launch_bounds__(256) void e2_kernel(const float* __restrict__ E,
    float* __restrict__ e2)
{
  int gid = blockIdx.x*256 + threadIdx.x;
  int wid = gid >> 6, lane = gid & 63;
  if (wid < 18*KK) {
    float4 v = *(const float4*)&E[(size_t)wid*DD + lane*4];
    float s = v.x*v.x + v.y*v.y + v.z*v.z + v.w*v.w;
    #pragma unroll
    for (int m = 1; m <= 32; m <<= 1) s += __shfl_xor(s, m);
    if (lane == 0) e2[wid] = s;
  }
}

// ---------------- convert E -> f16 plane ----------------
__global__ __launch_bounds__(256) void cvt_e16_kernel(const float* __restrict__ E,
    _Float16* __restrict__ E16)
{
  size_t i = ((size_t)blockIdx.x*256 + threadIdx.x)*8;
  float4 u = *(const float4*)&E[i];
  float4 v = *(const float4*)&E[i+4];
  half8_t h;
  h[0]=(_Float16)u.x; h[1]=(_Float16)u.y; h[2]=(_Float16)u.z; h[3]=(_Float16)u.w;
  h[4]=(_Float16)v.x; h[5]=(_Float16)v.y; h[6]=(_Float16)v.z; h[7]=(_Float16)v.w;
  *(half8_t*)&E16[i] = h;
}

// ---------------- FUSED encode: all 22 books, one kernel ----------------
// 256 blocks x 64 rows, 256 threads = 4 waves (escapes the 128-VGPR wall of
// 8-wave blocks). Each wave holds ALL 64 rows' A fragments in registers and
// owns a 512-code quarter. Top-3 tracking -> cheap pairwise fp64 refine;
// full fp64 re-rank only when 3rd-best is within EPS of best (rare).
__global__ __launch_bounds__(256) __attribute__((amdgpu_waves_per_eu(1)))
void fused_encode_kernel(
    const float* __restrict__ xs_g, const float* __restrict__ xa_g,
    const float* __restrict__ E, const _Float16* __restrict__ E16,
    const float* __restrict__ e2, int* __restrict__ codes0,
    float* __restrict__ codes_f, float* __restrict__ aco_g)
{
  const int tid = threadIdx.x;
  const int lane = tid & 63, wave = tid >> 6;   // 4 waves
  const int ln15 = lane & 15, lq = lane >> 4;   // lq 0..3
  const int row0 = blockIdx.x * 64;

  __shared__ float Z[64][ZSTR];                 // residual panel (66.5KB)
  __shared__ float L1v[4][64], L2v[4][64], L3v[4][64];
  __shared__ int   L1i[4][64], L2i[4][64];
  __shared__ int   codes_s[64];
  __shared__ int   flist[64], plist[64];
  __shared__ int   nfull, npair;
  __shared__ float zrow[DD];
  __shared__ double Rv[4];
  __shared__ int    Ri[4];

  const int ldr = tid & 63, cg = tid >> 6;      // panel-load / aco mapping
  const int sr = tid >> 2, sg = tid & 3;        // subtract mapping (4 thr/row)

  for (int ib = 0; ib < NBOOKS; ++ib) {
    const int book = (ib <= 17) ? ib : 17;
    const float*     Eb   = E   + (size_t)book*KK*DD;
    const _Float16*  E16b = E16 + (size_t)book*KK*DD;
    const float*     e2b  = e2  + (size_t)book*KK;

    if (ib <= 1) {                              // ib0: xs panel; ib1: xa panel
      const float* src = (ib == 0) ? xs_g : xa_g;
      const float* sp = src + (size_t)(row0 + ldr)*DD + cg*64;
      #pragma unroll
      for (int j = 0; j < 16; ++j)
        *(float4*)&Z[ldr][cg*64 + j*4] = *(const float4*)(sp + j*4);
    }
    if (tid == 0) { nfull = 0; npair = 0; }
    __syncthreads();                            // S1

    // ---- A fragments from LDS (f32 -> f16): all 64 rows, full K ----
    half8_t A[4][8];
    #pragma unroll
    for (int mt = 0; mt < 4; ++mt) {
      #pragma unroll
      for (int ks = 0; ks < 8; ++ks) {
        const float* zp = &Z[mt*16 + ln15][lq*8 + ks*32];
        float4 u = *(const float4*)zp;
        float4 v = *(const float4*)(zp + 4);
        half8_t a;
        a[0]=(_Float16)u.x; a[1]=(_Float16)u.y; a[2]=(_Float16)u.z; a[3]=(_Float16)u.w;
        a[4]=(_Float16)v.x; a[5]=(_Float16)v.y; a[6]=(_Float16)v.z; a[7]=(_Float16)v.w;
        A[mt][ks] = a;
      }
    }

    float b1[4][4], b2[4][4], b3[4][4]; int i1[4][4], i2[4][4];
    #pragma unroll
    for (int mt = 0; mt < 4; ++mt)
      #pragma unroll
      for (int j = 0; j < 4; ++j) {
        b1[mt][j] = FLT_MAX; b2[mt][j] = FLT_MAX; b3[mt][j] = FLT_MAX;
        i1[mt][j] = 0x7fffffff; i2[mt][j] = 0x7fffffff;
      }

    const _Float16* ebase = E16b + (size_t)(wave*512 + ln15)*DD + lq*8;

    half8_t B[8], NB[4];
    #pragma unroll
    for (int ks = 0; ks < 8; ++ks) B[ks] = *(const half8_t*)(ebase + ks*32);

    for (int nt = 0; nt < 32; ++nt) {
      const _Float16* nx = ebase + (size_t)(nt+1)*16*DD;
      if (nt < 31) {
        NB[0] = *(const half8_t*)(nx + 0*32);
        NB[1] = *(const half8_t*)(nx + 1*32);
        NB[2] = *(const half8_t*)(nx + 2*32);
        NB[3] = *(const half8_t*)(nx + 3*32);
      }
      int code = wave*512 + nt*16 + ln15;
      float e2v = e2b[code];
      f32x4 acc[4];
      #pragma unroll
      for (int mt = 0; mt < 4; ++mt) acc[mt] = (f32x4){0.f,0.f,0.f,0.f};
      #pragma unroll
      for (int ks = 0; ks < 8; ++ks) {
        #pragma unroll
        for (int mt = 0; mt < 4; ++mt)
          acc[mt] = __builtin_amdgcn_mfma_f32_16x16x32_f16(A[mt][ks], B[ks], acc[mt], 0, 0, 0);
      }
      // C/D: col(code)=lane&15, row=(lane>>4)*4+reg
      #pragma unroll
      for (int mt = 0; mt < 4; ++mt)
        #pragma unroll
        for (int j = 0; j < 4; ++j) {
          float u = fmaf(-2.f, acc[mt][j], e2v);
          insert3(b1[mt][j], i1[mt][j], b2[mt][j], i2[mt][j], b3[mt][j], u, code);
        }
      if (nt < 31) {
        B[0] = NB[0]; B[1] = NB[1]; B[2] = NB[2]; B[3] = NB[3];
        B[4] = *(const half8_t*)(nx + 4*32);
        B[5] = *(const half8_t*)(nx + 5*32);
        B[6] = *(const half8_t*)(nx + 6*32);
        B[7] = *(const half8_t*)(nx + 7*32);
      }
    }

    // ---- in-wave reduce over the 16 code-columns, then cross-wave ----
    #pragma unroll
    for (int mt = 0; mt < 4; ++mt)
      #pragma unroll
      for (int j = 0; j < 4; ++j) {
        float v1 = b1[mt][j], v2 = b2[mt][j], v3 = b3[mt][j];
        int a1 = i1[mt][j], a2 = i2[mt][j];
        #pragma unroll
        for (int m = 1; m <= 8; m <<= 1) {
          float w1 = __shfl_xor(v1, m), w2 = __shfl_xor(v2, m), w3 = __shfl_xor(v3, m);
          int   j1 = __shfl_xor(a1, m), j2 = __shfl_xor(a2, m);
          merge5(v1, a1, v2, a2, v3, w1, j1, w2, j2, w3);
        }
        if (ln15 == 0) {
          int rl = mt*16 + lq*4 + j;
          L1v[wave][rl] = v1; L1i[wave][rl] = a1;
          L2v[wave][rl] = v2; L2i[wave][rl] = a2;
          L3v[wave][rl] = v3;
        }
      }
    __syncthreads();                            // S2
    if (tid < 64) {
      float v1 = L1v[0][tid], v2 = L2v[0][tid], v3 = L3v[0][tid];
      int a1 = L1i[0][tid], a2 = L2i[0][tid];
      #pragma unroll
      for (int w = 1; w < 4; ++w)
        merge5(v1, a1, v2, a2, v3,
               L1v[w][tid], L1i[w][tid], L2v[w][tid], L2i[w][tid], L3v[w][tid]);
      codes_s[tid] = a1;
      int rg = row0 + tid;
      codes_f[((size_t)(rg >> 12)*NBOOKS + ib)*TT + (rg & (TT-1))] = (float)a1;
      if (ib == 0) codes0[rg] = a1;
      if (v3 - v1 < EPS_FULL) {
        flist[atomicAdd(&nfull, 1)] = tid;
      } else if (v2 - v1 < EPS_PAIR) {
        plist[atomicAdd(&npair, 1)] = tid | (a1 << 6) | (a2 << 17);
      }
    }
    __syncthreads();                            // S3

    // ---- full fp64 re-rank (rare: 3rd-best within EPS of best) ----
    int nfl = nfull;
    for (int f = 0; f < nfl; ++f) {
      int row = flist[f];
      if (tid < 64)
        *(float4*)&zrow[tid*4] = *(const float4*)&Z[row][tid*4];
      __syncthreads();
      double bestv = DBL_MAX; int besti = 0x7fffffff;
      #pragma unroll
      for (int q = 0; q < 8; ++q) {
        int k = q*256 + tid;
        const float* er = Eb + (size_t)k*DD;
        double s = 0.0;
        for (int d = 0; d < DD; d += 4) {
          float4 e = *(const float4*)(er + d);
          double d0 = (double)zrow[d+0] - (double)e.x; s += d0*d0;
          double d1 = (double)zrow[d+1] - (double)e.y; s += d1*d1;
          double d2 = (double)zrow[d+2] - (double)e.z; s += d2*d2;
          double d3 = (double)zrow[d+3] - (double)e.w; s += d3*d3;
        }
        if (s < bestv || (s == bestv && k < besti)) { bestv = s; besti = k; }
      }
      #pragma unroll
      for (int m = 1; m <= 32; m <<= 1) {
        double ov = __shfl_xor(bestv, m);
        int    oi = __shfl_xor(besti, m);
        if (ov < bestv || (ov == bestv && oi < besti)) { bestv = ov; besti = oi; }
      }
      if (lane == 0) { Rv[wave] = bestv; Ri[wave] = besti; }
      __syncthreads();
      if (tid == 0) {
        double bvv = Rv[0]; int bii = Ri[0];
        #pragma unroll
        for (int w = 1; w < 4; ++w)
          if (Rv[w] < bvv || (Rv[w] == bvv && Ri[w] < bii)) { bvv = Rv[w]; bii = Ri[w]; }
        codes_s[row] = bii;
        int rg = row0 + row;
        codes_f[((size_t)(rg >> 12)*NBOOKS + ib)*TT + (rg & (TT-1))] = (float)bii;
        if (ib == 0) codes0[rg] = bii;
      }
      __syncthreads();
    }

    // ---- pairwise fp64 refine: one wave per flagged row, compares top-2 ----
    {
      int npr = npair;
      for (int f = wave; f < npr; f += 4) {
        int pk = plist[f];
        int row = pk & 63;
        int c1 = (pk >> 6) & 2047, c2 = (pk >> 17) & 2047;
        int cc = (lane < 32) ? c1 : c2;
        const float* er = Eb + (size_t)cc*DD + (lane & 31)*8;
        const float* zr = &Z[row][(lane & 31)*8];
        double s = 0.0;
        #pragma unroll
        for (int d = 0; d < 8; ++d) {
          double df = (double)zr[d] - (double)er[d];
          s += df*df;
        }
        #pragma unroll
        for (int m = 1; m <= 16; m <<= 1) s += __shfl_xor(s, m);
        double so = __shfl_xor(s, 32);
        double d1 = (lane < 32) ? s : so;
        double d2 = (lane < 32) ? so : s;
        int win = (d2 < d1 || (d2 == d1 && c2 < c1)) ? c2 : c1;
        if (lane == 0) {
          codes_s[row] = win;
          int rg = row0 + row;
          codes_f[((size_t)(rg >> 12)*NBOOKS + ib)*TT + (rg & (TT-1))] = (float)win;
          if (ib == 0) codes0[rg] = win;
        }
      }
    }
    __syncthreads();                            // S4: codes_s final

    // ---- f32 residual subtract in LDS (acoustic books only) ----
    if (ib >= 1) {
      int code = codes_s[sr];
      const float* er = Eb + (size_t)code*DD;
      #pragma unroll
      for (int j = 0; j < 16; ++j) {
        int c = sg*4 + j*16;
        float4 e = *(const float4*)(er + c);
        float4 z = *(const float4*)&Z[sr][c];
        z.x -= e.x; z.y -= e.y; z.z -= e.z; z.w -= e.w;
        *(float4*)&Z[sr][c] = z;
      }
    }
    __syncthreads();                            // S5: Z stable for next book
  }

  // ---- aco = xa_initial - xa_final ----
  {
    const float* xp = xa_g + (size_t)(row0 + ldr)*DD + cg*64;
    float*       ap = aco_g + (size_t)(row0 + ldr)*DD + cg*64;
    #pragma unroll
    for (int j = 0; j < 16; ++j) {
      float4 x0 = *(const float4*)(xp + j*4);
      float4 zf = *(const float4*)&Z[ldr][cg*64 + j*4];
      float4 o;
      o.x = x0.x - zf.x; o.y = x0.y - zf.y; o.z = x0.z - zf.z; o.w = x0.w - zf.w;
      *(float4*)(ap + j*4) = o;
    }
  }
}

// ---------------- decode ----------------
__global__ __launch_bounds__(256) void final_kernel(
    const float* __restrict__ Wos, const float* __restrict__ Woa,
    const float* __restrict__ E0, const int* __restrict__ codes0,
    const float* __restrict__ aco, float* __restrict__ out)
{
  __shared__ float wsl[16*68], wal[16*68], sml[16*68], acl[16*68];
  const int tid = threadIdx.x;
  const int t0 = blockIdx.x*64, c0 = blockIdx.y*64, b = blockIdx.z;
  const int u = tid & 63, dq = tid >> 6;
  const int tx = tid & 15, ty = tid >> 4;
  int code = codes0[b*TT + t0 + u];
  const float* smr = E0 + (size_t)code*DD;
  const float* acr = aco + (size_t)(b*TT + t0 + u)*DD;
  const float* wsr = Wos + (size_t)(c0+u)*DD;
  const float* war = Woa + (size_t)(c0+u)*DD;
  float accS[4][4] = {{0}}, accA[4][4] = {{0}};
  for (int dc0 = 0; dc0 < DD; dc0 += 16) {
    __syncthreads();
    float4 v;
    v = *(const float4*)(wsr + dc0 + dq*4);
    wsl[(dq*4+0)*68+u]=v.x; wsl[(dq*4+1)*68+u]=v.y; wsl[(dq*4+2)*68+u]=v.z; wsl[(dq*4+3)*68+u]=v.w;
    v = *(const float4*)(war + dc0 + dq*4);
    wal[(dq*4+0)*68+u]=v.x; wal[(dq*4+1)*68+u]=v.y; wal[(dq*4+2)*68+u]=v.z; wal[(dq*4+3)*68+u]=v.w;
    v = *(const float4*)(smr + dc0 + dq*4);
    sml[(dq*4+0)*68+u]=v.x; sml[(dq*4+1)*68+u]=v.y; sml[(dq*4+2)*68+u]=v.z; sml[(dq*4+3)*68+u]=v.w;
    v = *(const float4*)(acr + dc0 + dq*4);
    acl[(dq*4+0)*68+u]=v.x; acl[(dq*4+1)*68+u]=v.y; acl[(dq*4+2)*68+u]=v.z; acl[(dq*4+3)*68+u]=v.w;
    __syncthreads();
    #pragma unroll
    for (int d = 0; d < 16; ++d) {
      float4 cs = *(const float4*)&wsl[d*68 + tx*4];
      float4 ca = *(const float4*)&wal[d*68 + tx*4];
      float4 ts = *(const float4*)&sml[d*68 + ty*4];
      float4 ta = *(const float4*)&acl[d*68 + ty*4];
      float csf[4]={cs.x,cs.y,cs.z,cs.w}, caf[4]={ca.x,ca.y,ca.z,ca.w};
      float tsf[4]={ts.x,ts.y,ts.z,ts.w}, taf[4]={ta.x,ta.y,ta.z,ta.w};
      #pragma unroll
      for (int i = 0; i < 4; ++i)
        #pragma unroll
        for (int j = 0; j < 4; ++j) {
          accS[i][j] = fmaf(csf[i], tsf[j], accS[i][j]);
          accA[i][j] = fmaf(caf[i], taf[j], accA[i][j]);
        }
    }
  }
  size_t ob = (size_t)b*CC*TT;
  #pragma unroll
  for (int i = 0; i < 4; ++i) {
    float4 r;
    r.x = accS[i][0] + accA[i][0];
    r.y = accS[i][1] + accA[i][1];
    r.z = accS[i][2] + accA[i][2];
    r.w = accS[i][3] + accA[i][3];
    *(float4*)&out[ob + (size_t)(c0 + tx*4 + i)*TT + t0 + ty*4] = r;
  }
}

extern "C" void kernel_launch(void* const* d_in, const int* in_sizes, int n_in,
                              void* d_out, int out_size, void* d_ws, size_t ws_size,
                              hipStream_t stream) {
  const float* x    = (const float*)d_in[0];
  const float* Wins = (const float*)d_in[1];
  const float* Wina = (const float*)d_in[2];
  const float* Wos  = (const float*)d_in[3];
  const float* Woa  = (const float*)d_in[4];
  const float* E    = (const float*)d_in[5];
  float* out = (float*)d_out;
  float* codes_f = out + (size_t)BB*CC*TT;

  // E16 plane lives in the front of d_out (18.9MB; codes_f starts at 33.6MB;
  // out[0:8.4M floats] fully overwritten by final_kernel afterwards).
  _Float16* E16 = (_Float16*)d_out;

  float* xs  = (float*)d_ws;
  float* xa  = xs + (size_t)MM*DD;
  float* aco = xa + (size_t)MM*DD;
  float* e2  = aco + (size_t)MM*DD;
  int* codes_i = (int*)(e2 + 18*KK);

  proj_kernel<<<dim3(TT/64, DD/64, BB), 256, 0, stream>>>(x, Wins, Wina, xs, xa);
  e2_kernel<<<(18*KK*64)/256, 256, 0, stream>>>(E, e2);
  cvt_e16_kernel<<<(18*KK*DD)/8/256, 256, 0, stream>>>(E, E16);

  fused_encode_kernel<<<MM/64, 256, 0, stream>>>(xs, xa, E, E16, e2,
                                                 codes_i, codes_f, aco);

  final_kernel<<<dim3(TT/64, CC/64, BB), 256, 0, stream>>>(Wos, Woa, E, codes_i, aco, out);
}

// Round 11
// 1880.510 us; speedup vs baseline: 2.2148x; 1.2904x over previous
//
#include <hip/hip_runtime.h>
#include <float.h>

#define TT 4096
#define BB 4
#define CC 512
#define DD 256
#define KK 2048
#define MM (BB*TT)        // 16384 rows (b,t)
#define NBOOKS 22
#define EPS_PAIR 0.3f
#define EPS_FULL 0.3f
#define ZSTR 260
#define RPB 32            // rows per block

typedef _Float16 half8_t __attribute__((ext_vector_type(8)));
typedef float f32x4 __attribute__((ext_vector_type(4)));

// ---- top-3 tracking: (best v1,i1), (second v2,i2), (third value v3) ----
// ties -> lower index (np.argmin semantics, resolved exactly in fp64 later)
__device__ __forceinline__ void insert3(float& v1, int& i1, float& v2, int& i2,
                                        float& v3, float u, int c) {
  if (u < v1 || (u == v1 && c < i1)) {
    v3 = v2; v2 = v1; i2 = i1; v1 = u; i1 = c;
  } else if (u < v2 || (u == v2 && c < i2)) {
    v3 = v2; v2 = u; i2 = c;
  } else {
    v3 = fminf(v3, u);
  }
}

__device__ __forceinline__ void merge5(float& v1, int& i1, float& v2, int& i2,
                                       float& v3,
                                       float w1, int j1, float w2, int j2, float w3) {
  if (w1 < v1 || (w1 == v1 && j1 < i1)) {
    if (v1 < w2 || (v1 == w2 && i1 < j2)) {
      v3 = fminf(v2, w2);
      v2 = v1; i2 = i1;
    } else {
      v3 = fminf(v1, w3);
      v2 = w2; i2 = j2;
    }
    v1 = w1; i1 = j1;
  } else {
    if (w1 < v2 || (w1 == v2 && j1 < i2)) {
      v3 = fminf(v2, w2);
      v2 = w1; i2 = j1;
    } else {
      v3 = fminf(w1, v3);
    }
  }
}

// ---------------- projection: xs = Win_s @ x, xa = Win_a @ x ----------------
__global__ __launch_bounds__(256) void proj_kernel(const float* __restrict__ x,
    const float* __restrict__ Ws, const float* __restrict__ Wa,
    float* __restrict__ xs, float* __restrict__ xa)
{
  __shared__ float xt[16*64];
  __shared__ float wsl[16*68];
  __shared__ float wal[16*68];
  const int tid = threadIdx.x;
  const int t0 = blockIdx.x*64, d0 = blockIdx.y*64, b = blockIdx.z;
  const int u = tid & 63, cq = tid >> 6;
  const int tx = tid & 15, ty = tid >> 4;
  const float* xb = x + (size_t)b*CC*TT;
  float accS[4][4] = {{0}}, accA[4][4] = {{0}};
  for (int c0 = 0; c0 < CC; c0 += 16) {
    __syncthreads();
    #pragma unroll
    for (int i = 0; i < 4; ++i) {
      int cc = cq*4 + i;
      xt[cc*64 + u] = xb[(size_t)(c0+cc)*TT + t0 + u];
    }
    {
      float4 wv = *(const float4*)&Ws[(size_t)(d0+u)*CC + c0 + cq*4];
      wsl[(cq*4+0)*68 + u] = wv.x; wsl[(cq*4+1)*68 + u] = wv.y;
      wsl[(cq*4+2)*68 + u] = wv.z; wsl[(cq*4+3)*68 + u] = wv.w;
      wv = *(const float4*)&Wa[(size_t)(d0+u)*CC + c0 + cq*4];
      wal[(cq*4+0)*68 + u] = wv.x; wal[(cq*4+1)*68 + u] = wv.y;
      wal[(cq*4+2)*68 + u] = wv.z; wal[(cq*4+3)*68 + u] = wv.w;
    }
    __syncthreads();
    #pragma unroll
    for (int cc = 0; cc < 16; ++cc) {
      float4 tq = *(const float4*)&xt[cc*64 + ty*4];
      float4 sq = *(const float4*)&wsl[cc*68 + tx*4];
      float4 aq = *(const float4*)&wal[cc*68 + tx*4];
      float tf[4] = {tq.x,tq.y,tq.z,tq.w};
      float sf[4] = {sq.x,sq.y,sq.z,sq.w};
      float af[4] = {aq.x,aq.y,aq.z,aq.w};
      #pragma unroll
      for (int i = 0; i < 4; ++i)
        #pragma unroll
        for (int j = 0; j < 4; ++j) {
          accS[i][j] = fmaf(tf[i], sf[j], accS[i][j]);
          accA[i][j] = fmaf(tf[i], af[j], accA[i][j]);
        }
    }
  }
  #pragma unroll
  for (int i = 0; i < 4; ++i) {
    size_t r = (size_t)b*TT + t0 + ty*4 + i;
    float4 o;
    o.x = accS[i][0]; o.y = accS[i][1]; o.z = accS[i][2]; o.w = accS[i][3];
    *(float4*)&xs[r*DD + d0 + tx*4] = o;
    o.x = accA[i][0]; o.y = accA[i][1]; o.z = accA[i][2]; o.w = accA[i][3];
    *(float4*)&xa[r*DD + d0 + tx*4] = o;
  }
}

// ---------------- e2[k] = sum_d E[k][d]^2 ----------------
__global__ __launch_bounds__(256) void e2_kernel(const float* __restrict__ E,
    float* __restrict__ e2)
{
  int gid = blockIdx.x*256 + threadIdx.x;
  int wid = gid >> 6, lane = gid & 63;
  if (wid < 18*KK) {
    float4 v = *(const float4*)&E[(size_t)wid*DD + lane*4];
    float s = v.x*v.x + v.y*v.y + v.z*v.z + v.w*v.w;
    #pragma unroll
    for (int m = 1; m <= 32; m <<= 1) s += __shfl_xor(s, m);
    if (lane == 0) e2[wid] = s;
  }
}

// ---------------- convert E -> f16 plane ----------------
__global__ __launch_bounds__(256) void cvt_e16_kernel(const float* __restrict__ E,
    _Float16* __restrict__ E16)
{
  size_t i = ((size_t)blockIdx.x*256 + threadIdx.x)*8;
  float4 u = *(const float4*)&E[i];
  float4 v = *(const float4*)&E[i+4];
  half8_t h;
  h[0]=(_Float16)u.x; h[1]=(_Float16)u.y; h[2]=(_Float16)u.z; h[3]=(_Float16)u.w;
  h[4]=(_Float16)v.x; h[5]=(_Float16)v.y; h[6]=(_Float16)v.z; h[7]=(_Float16)v.w;
  *(half8_t*)&E16[i] = h;
}

// ---------------- FUSED encode: all 22 books, one kernel ----------------
// 512 blocks x 32 rows, 256 threads = 4 waves, ~37KB LDS + ~180 VGPR
// => 2 blocks/CU = 2 waves/SIMD (TLP to hide L2/MFMA/LDS latency).
// Each wave: A[2][8] (32 rows, full K, in registers) x 512-code quarter.
// Top-3 tracking -> cheap pairwise fp64 refine; full fp64 re-rank rare.
__global__ __launch_bounds__(256) __attribute__((amdgpu_waves_per_eu(2)))
void fused_encode_kernel(
    const float* __restrict__ xs_g, const float* __restrict__ xa_g,
    const float* __restrict__ E, const _Float16* __restrict__ E16,
    const float* __restrict__ e2, int* __restrict__ codes0,
    float* __restrict__ codes_f, float* __restrict__ aco_g)
{
  const int tid = threadIdx.x;
  const int lane = tid & 63, wave = tid >> 6;   // 4 waves
  const int ln15 = lane & 15, lq = lane >> 4;   // lq 0..3
  const int row0 = blockIdx.x * RPB;

  __shared__ float Z[RPB][ZSTR];                // residual panel (~33KB)
  __shared__ float L1v[4][RPB], L2v[4][RPB], L3v[4][RPB];
  __shared__ int   L1i[4][RPB], L2i[4][RPB];
  __shared__ int   codes_s[RPB];
  __shared__ int   flist[RPB], plist[RPB];
  __shared__ int   nfull, npair;
  __shared__ float zrow[DD];
  __shared__ double Rv[4];
  __shared__ int    Ri[4];

  const int ldr = tid & 31, cg = tid >> 5;      // panel-load / aco mapping (8 grp x 32 floats)
  const int sr = tid >> 3, sg = tid & 7;        // subtract mapping (8 thr/row)

  for (int ib = 0; ib < NBOOKS; ++ib) {
    const int book = (ib <= 17) ? ib : 17;
    const float*     Eb   = E   + (size_t)book*KK*DD;
    const _Float16*  E16b = E16 + (size_t)book*KK*DD;
    const float*     e2b  = e2  + (size_t)book*KK;

    if (ib <= 1) {                              // ib0: xs panel; ib1: xa panel
      const float* src = (ib == 0) ? xs_g : xa_g;
      const float* sp = src + (size_t)(row0 + ldr)*DD + cg*32;
      #pragma unroll
      for (int j = 0; j < 8; ++j)
        *(float4*)&Z[ldr][cg*32 + j*4] = *(const float4*)(sp + j*4);
    }
    if (tid == 0) { nfull = 0; npair = 0; }
    __syncthreads();                            // S1

    // ---- A fragments from LDS (f32 -> f16): 32 rows, full K ----
    half8_t A[2][8];
    #pragma unroll
    for (int mt = 0; mt < 2; ++mt) {
      #pragma unroll
      for (int ks = 0; ks < 8; ++ks) {
        const float* zp = &Z[mt*16 + ln15][lq*8 + ks*32];
        float4 u = *(const float4*)zp;
        float4 v = *(const float4*)(zp + 4);
        half8_t a;
        a[0]=(_Float16)u.x; a[1]=(_Float16)u.y; a[2]=(_Float16)u.z; a[3]=(_Float16)u.w;
        a[4]=(_Float16)v.x; a[5]=(_Float16)v.y; a[6]=(_Float16)v.z; a[7]=(_Float16)v.w;
        A[mt][ks] = a;
      }
    }

    float b1[2][4], b2[2][4], b3[2][4]; int i1[2][4], i2[2][4];
    #pragma unroll
    for (int mt = 0; mt < 2; ++mt)
      #pragma unroll
      for (int j = 0; j < 4; ++j) {
        b1[mt][j] = FLT_MAX; b2[mt][j] = FLT_MAX; b3[mt][j] = FLT_MAX;
        i1[mt][j] = 0x7fffffff; i2[mt][j] = 0x7fffffff;
      }

    const _Float16* ebase = E16b + (size_t)(wave*512 + ln15)*DD + lq*8;

    half8_t B[8], NB[4];
    #pragma unroll
    for (int ks = 0; ks < 8; ++ks) B[ks] = *(const half8_t*)(ebase + ks*32);

    for (int nt = 0; nt < 32; ++nt) {
      const _Float16* nx = ebase + (size_t)(nt+1)*16*DD;
      if (nt < 31) {
        NB[0] = *(const half8_t*)(nx + 0*32);
        NB[1] = *(const half8_t*)(nx + 1*32);
        NB[2] = *(const half8_t*)(nx + 2*32);
        NB[3] = *(const half8_t*)(nx + 3*32);
      }
      int code = wave*512 + nt*16 + ln15;
      float e2v = e2b[code];
      f32x4 acc[2];
      #pragma unroll
      for (int mt = 0; mt < 2; ++mt) acc[mt] = (f32x4){0.f,0.f,0.f,0.f};
      #pragma unroll
      for (int ks = 0; ks < 8; ++ks) {
        #pragma unroll
        for (int mt = 0; mt < 2; ++mt)
          acc[mt] = __builtin_amdgcn_mfma_f32_16x16x32_f16(A[mt][ks], B[ks], acc[mt], 0, 0, 0);
      }
      // C/D: col(code)=lane&15, row=(lane>>4)*4+reg
      #pragma unroll
      for (int mt = 0; mt < 2; ++mt)
        #pragma unroll
        for (int j = 0; j < 4; ++j) {
          float u = fmaf(-2.f, acc[mt][j], e2v);
          insert3(b1[mt][j], i1[mt][j], b2[mt][j], i2[mt][j], b3[mt][j], u, code);
        }
      if (nt < 31) {
        B[0] = NB[0]; B[1] = NB[1]; B[2] = NB[2]; B[3] = NB[3];
        B[4] = *(const half8_t*)(nx + 4*32);
        B[5] = *(const half8_t*)(nx + 5*32);
        B[6] = *(const half8_t*)(nx + 6*32);
        B[7] = *(const half8_t*)(nx + 7*32);
      }
    }

    // ---- in-wave reduce over the 16 code-columns, then cross-wave ----
    #pragma unroll
    for (int mt = 0; mt < 2; ++mt)
      #pragma unroll
      for (int j = 0; j < 4; ++j) {
        float v1 = b1[mt][j], v2 = b2[mt][j], v3 = b3[mt][j];
        int a1 = i1[mt][j], a2 = i2[mt][j];
        #pragma unroll
        for (int m = 1; m <= 8; m <<= 1) {
          float w1 = __shfl_xor(v1, m), w2 = __shfl_xor(v2, m), w3 = __shfl_xor(v3, m);
          int   j1 = __shfl_xor(a1, m), j2 = __shfl_xor(a2, m);
          merge5(v1, a1, v2, a2, v3, w1, j1, w2, j2, w3);
        }
        if (ln15 == 0) {
          int rl = mt*16 + lq*4 + j;
          L1v[wave][rl] = v1; L1i[wave][rl] = a1;
          L2v[wave][rl] = v2; L2i[wave][rl] = a2;
          L3v[wave][rl] = v3;
        }
      }
    __syncthreads();                            // S2
    if (tid < RPB) {
      float v1 = L1v[0][tid], v2 = L2v[0][tid], v3 = L3v[0][tid];
      int a1 = L1i[0][tid], a2 = L2i[0][tid];
      #pragma unroll
      for (int w = 1; w < 4; ++w)
        merge5(v1, a1, v2, a2, v3,
               L1v[w][tid], L1i[w][tid], L2v[w][tid], L2i[w][tid], L3v[w][tid]);
      codes_s[tid] = a1;
      int rg = row0 + tid;
      codes_f[((size_t)(rg >> 12)*NBOOKS + ib)*TT + (rg & (TT-1))] = (float)a1;
      if (ib == 0) codes0[rg] = a1;
      if (v3 - v1 < EPS_FULL) {
        flist[atomicAdd(&nfull, 1)] = tid;
      } else if (v2 - v1 < EPS_PAIR) {
        plist[atomicAdd(&npair, 1)] = tid | (a1 << 6) | (a2 << 17);
      }
    }
    __syncthreads();                            // S3

    // ---- full fp64 re-rank (rare: 3rd-best within EPS of best) ----
    int nfl = nfull;
    for (int f = 0; f < nfl; ++f) {
      int row = flist[f];
      if (tid < 64)
        *(float4*)&zrow[tid*4] = *(const float4*)&Z[row][tid*4];
      __syncthreads();
      double bestv = DBL_MAX; int besti = 0x7fffffff;
      #pragma unroll
      for (int q = 0; q < 8; ++q) {
        int k = q*256 + tid;
        const float* er = Eb + (size_t)k*DD;
        double s = 0.0;
        for (int d = 0; d < DD; d += 4) {
          float4 e = *(const float4*)(er + d);
          double d0 = (double)zrow[d+0] - (double)e.x; s += d0*d0;
          double d1 = (double)zrow[d+1] - (double)e.y; s += d1*d1;
          double d2 = (double)zrow[d+2] - (double)e.z; s += d2*d2;
          double d3 = (double)zrow[d+3] - (double)e.w; s += d3*d3;
        }
        if (s < bestv || (s == bestv && k < besti)) { bestv = s; besti = k; }
      }
      #pragma unroll
      for (int m = 1; m <= 32; m <<= 1) {
        double ov = __shfl_xor(bestv, m);
        int    oi = __shfl_xor(besti, m);
        if (ov < bestv || (ov == bestv && oi < besti)) { bestv = ov; besti = oi; }
      }
      if (lane == 0) { Rv[wave] = bestv; Ri[wave] = besti; }
      __syncthreads();
      if (tid == 0) {
        double bvv = Rv[0]; int bii = Ri[0];
        #pragma unroll
        for (int w = 1; w < 4; ++w)
          if (Rv[w] < bvv || (Rv[w] == bvv && Ri[w] < bii)) { bvv = Rv[w]; bii = Ri[w]; }
        codes_s[row] = bii;
        int rg = row0 + row;
        codes_f[((size_t)(rg >> 12)*NBOOKS + ib)*TT + (rg & (TT-1))] = (float)bii;
        if (ib == 0) codes0[rg] = bii;
      }
      __syncthreads();
    }

    // ---- pairwise fp64 refine: one wave per flagged row, compares top-2 ----
    {
      int npr = npair;
      for (int f = wave; f < npr; f += 4) {
        int pk = plist[f];
        int row = pk & 63;
        int c1 = (pk >> 6) & 2047, c2 = (pk >> 17) & 2047;
        int cc = (lane < 32) ? c1 : c2;
        const float* er = Eb + (size_t)cc*DD + (lane & 31)*8;
        const float* zr = &Z[row][(lane & 31)*8];
        double s = 0.0;
        #pragma unroll
        for (int d = 0; d < 8; ++d) {
          double df = (double)zr[d] - (double)er[d];
          s += df*df;
        }
        #pragma unroll
        for (int m = 1; m <= 16; m <<= 1) s += __shfl_xor(s, m);
        double so = __shfl_xor(s, 32);
        double d1 = (lane < 32) ? s : so;
        double d2 = (lane < 32) ? so : s;
        int win = (d2 < d1 || (d2 == d1 && c2 < c1)) ? c2 : c1;
        if (lane == 0) {
          codes_s[row] = win;
          int rg = row0 + row;
          codes_f[((size_t)(rg >> 12)*NBOOKS + ib)*TT + (rg & (TT-1))] = (float)win;
          if (ib == 0) codes0[rg] = win;
        }
      }
    }
    __syncthreads();                            // S4: codes_s final

    // ---- f32 residual subtract in LDS (acoustic books only) ----
    if (ib >= 1) {
      int code = codes_s[sr];
      const float* er = Eb + (size_t)code*DD;
      #pragma unroll
      for (int j = 0; j < 8; ++j) {
        int c = sg*4 + j*32;
        float4 e = *(const float4*)(er + c);
        float4 z = *(const float4*)&Z[sr][c];
        z.x -= e.x; z.y -= e.y; z.z -= e.z; z.w -= e.w;
        *(float4*)&Z[sr][c] = z;
      }
    }
    __syncthreads();                            // S5: Z stable for next book
  }

  // ---- aco = xa_initial - xa_final ----
  {
    const float* xp = xa_g + (size_t)(row0 + ldr)*DD + cg*32;
    float*       ap = aco_g + (size_t)(row0 + ldr)*DD + cg*32;
    #pragma unroll
    for (int j = 0; j < 8; ++j) {
      float4 x0 = *(const float4*)(xp + j*4);
      float4 zf = *(const float4*)&Z[ldr][cg*32 + j*4];
      float4 o;
      o.x = x0.x - zf.x; o.y = x0.y - zf.y; o.z = x0.z - zf.z; o.w = x0.w - zf.w;
      *(float4*)(ap + j*4) = o;
    }
  }
}

// ---------------- decode ----------------
__global__ __launch_bounds__(256) void final_kernel(
    const float* __restrict__ Wos, const float* __restrict__ Woa,
    const float* __restrict__ E0, const int* __restrict__ codes0,
    const float* __restrict__ aco, float* __restrict__ out)
{
  __shared__ float wsl[16*68], wal[16*68], sml[16*68], acl[16*68];
  const int tid = threadIdx.x;
  const int t0 = blockIdx.x*64, c0 = blockIdx.y*64, b = blockIdx.z;
  const int u = tid & 63, dq = tid >> 6;
  const int tx = tid & 15, ty = tid >> 4;
  int code = codes0[b*TT + t0 + u];
  const float* smr = E0 + (size_t)code*DD;
  const float* acr = aco + (size_t)(b*TT + t0 + u)*DD;
  const float* wsr = Wos + (size_t)(c0+u)*DD;
  const float* war = Woa + (size_t)(c0+u)*DD;
  float accS[4][4] = {{0}}, accA[4][4] = {{0}};
  for (int dc0 = 0; dc0 < DD; dc0 += 16) {
    __syncthreads();
    float4 v;
    v = *(const float4*)(wsr + dc0 + dq*4);
    wsl[(dq*4+0)*68+u]=v.x; wsl[(dq*4+1)*68+u]=v.y; wsl[(dq*4+2)*68+u]=v.z; wsl[(dq*4+3)*68+u]=v.w;
    v = *(const float4*)(war + dc0 + dq*4);
    wal[(dq*4+0)*68+u]=v.x; wal[(dq*4+1)*68+u]=v.y; wal[(dq*4+2)*68+u]=v.z; wal[(dq*4+3)*68+u]=v.w;
    v = *(const float4*)(smr + dc0 + dq*4);
    sml[(dq*4+0)*68+u]=v.x; sml[(dq*4+1)*68+u]=v.y; sml[(dq*4+2)*68+u]=v.z; sml[(dq*4+3)*68+u]=v.w;
    v = *(const float4*)(acr + dc0 + dq*4);
    acl[(dq*4+0)*68+u]=v.x; acl[(dq*4+1)*68+u]=v.y; acl[(dq*4+2)*68+u]=v.z; acl[(dq*4+3)*68+u]=v.w;
    __syncthreads();
    #pragma unroll
    for (int d = 0; d < 16; ++d) {
      float4 cs = *(const float4*)&wsl[d*68 + tx*4];
      float4 ca = *(const float4*)&wal[d*68 + tx*4];
      float4 ts = *(const float4*)&sml[d*68 + ty*4];
      float4 ta = *(const float4*)&acl[d*68 + ty*4];
      float csf[4]={cs.x,cs.y,cs.z,cs.w}, caf[4]={ca.x,ca.y,ca.z,ca.w};
      float tsf[4]={ts.x,ts.y,ts.z,ts.w}, taf[4]={ta.x,ta.y,ta.z,ta.w};
      #pragma unroll
      for (int i = 0; i < 4; ++i)
        #pragma unroll
        for (int j = 0; j < 4; ++j) {
          accS[i][j] = fmaf(csf[i], tsf[j], accS[i][j]);
          accA[i][j] = fmaf(caf[i], taf[j], accA[i][j]);
        }
    }
  }
  size_t ob = (size_t)b*CC*TT;
  #pragma unroll
  for (int i = 0; i < 4; ++i) {
    float4 r;
    r.x = accS[i][0] + accA[i][0];
    r.y = accS[i][1] + accA[i][1];
    r.z = accS[i][2] + accA[i][2];
    r.w = accS[i][3] + accA[i][3];
    *(float4*)&out[ob + (size_t)(c0 + tx*4 + i)*TT + t0 + ty*4] = r;
  }
}

extern "C" void kernel_launch(void* const* d_in, const int* in_sizes, int n_in,
                              void* d_out, int out_size, void* d_ws, size_t ws_size,
                              hipStream_t stream) {
  const float* x    = (const float*)d_in[0];
  const float* Wins = (const float*)d_in[1];
  const float* Wina = (const float*)d_in[2];
  const float* Wos  = (const float*)d_in[3];
  const float* Woa  = (const float*)d_in[4];
  const float* E    = (const float*)d_in[5];
  float* out = (float*)d_out;
  float* codes_f = out + (size_t)BB*CC*TT;

  // E16 plane lives in the front of d_out (18.9MB; codes_f starts at 33.6MB;
  // out[0:8.4M floats] fully overwritten by final_kernel afterwards).
  _Float16* E16 = (_Float16*)d_out;

  float* xs  = (float*)d_ws;
  float* xa  = xs + (size_t)MM*DD;
  float* aco = xa + (size_t)MM*DD;
  float* e2  = aco + (size_t)MM*DD;
  int* codes_i = (int*)(e2 + 18*KK);

  proj_kernel<<<dim3(TT/64, DD/64, BB), 256, 0, stream>>>(x, Wins, Wina, xs, xa);
  e2_kernel<<<(18*KK*64)/256, 256, 0, stream>>>(E, e2);
  cvt_e16_kernel<<<(18*KK*DD)/8/256, 256, 0, stream>>>(E, E16);

  fused_encode_kernel<<<MM/RPB, 256, 0, stream>>>(xs, xa, E, E16, e2,
                                                  codes_i, codes_f, aco);

  final_kernel<<<dim3(TT/64, CC/64, BB), 256, 0, stream>>>(Wos, Woa, E, codes_i, aco, out);
}